// Round 30
// baseline (291.242 us; speedup 1.0000x reference)
//
#include <hip/hip_runtime.h>
#include <hip/hip_bf16.h>
#include <math.h>

#define DIM      512
#define D_STATE  16
#define D_CONV   4
#define D_INNER  1024
#define DT_RANK  32
#define B_SZ     2
#define SEQ      2048
#define NTOK     (B_SZ * SEQ)   // 4096
#define CHUNK    64
#define NCH      (SEQ / CHUNK)  // 32
#define NC_PAD   1152
#define PG       8
#define NPG      (CHUNK / PG)   // 8

// strides (elements)
#define XCB_STR   4194304   // [4096][1024] bf16 per dir (shorts)
#define WCB_STR   1179648   // [1152][1024] bf16 per dir (shorts)
#define BC_STR    131072    // [4096][32] fp32 per dir (floats)
#define CH_STR    1048576   // B_SZ*NCH*1024*16 fp32 per dir (floats)

typedef __attribute__((ext_vector_type(8))) short bf16x8;
typedef __attribute__((ext_vector_type(4))) float f32x4;

__device__ __forceinline__ short f2bf(float f) {
    unsigned u = __float_as_uint(f);
    u += 0x7fffu + ((u >> 16) & 1u);
    return (short)(u >> 16);
}
__device__ __forceinline__ float bf2f(short v) {
    return __uint_as_float(((unsigned)(unsigned short)v) << 16);
}
__device__ __forceinline__ float softplus_fast(float v) {
    return (v > 20.f) ? v : __logf(1.f + __expf(v));
}

// ---------------- fp32 -> bf16 bulk convert (n % 8 == 0) ------------------
__global__ __launch_bounds__(256)
void cvt_bf16(const float* __restrict__ src, short* __restrict__ dst, int n)
{
    int i = (blockIdx.x * 256 + threadIdx.x) * 8;
    if (i >= n) return;
    float4 a = *(const float4*)(src + i);
    float4 b = *(const float4*)(src + i + 4);
    bf16x8 v;
    v[0] = f2bf(a.x); v[1] = f2bf(a.y); v[2] = f2bf(a.z); v[3] = f2bf(a.w);
    v[4] = f2bf(b.x); v[5] = f2bf(b.y); v[6] = f2bf(b.z); v[7] = f2bf(b.w);
    *(bf16x8*)(dst + i) = v;
}

// Wcat[512][2048] = [out_w_f | out_w_r] along K (bf16)
__global__ __launch_bounds__(256)
void cvt_wcat(const float* __restrict__ wf, const float* __restrict__ wr,
              short* __restrict__ Wcat)
{
    int idx = blockIdx.x * 256 + threadIdx.x;
    if (idx >= 512 * 2048) return;
    int n = idx >> 11, col = idx & 2047;
    const float* src = (col < 1024) ? wf : wr;
    Wcat[idx] = f2bf(src[n * 1024 + (col & 1023)]);
}

// ---------------- combined projection weight, both dirs ------------------
__global__ __launch_bounds__(256)
void build_wc(const float* __restrict__ xp0, const float* __restrict__ xp1,
              const float* __restrict__ dw0, const float* __restrict__ dw1,
              short* __restrict__ Wcb)
{
    const int dir = blockIdx.y;
    int idx = blockIdx.x * 256 + threadIdx.x;
    if (idx >= NC_PAD * D_INNER) return;
    const float* xproj_w = dir ? xp1 : xp0;
    const float* dt_w    = dir ? dw1 : dw0;
    int i = idx >> 10, k = idx & 1023;
    float v;
    if (i < 1024) {
        v = 0.f;
#pragma unroll
        for (int r = 0; r < 32; ++r)
            v = fmaf(dt_w[i * 32 + r], xproj_w[r * 1024 + k], v);
    } else if (i < 1056) {
        v = xproj_w[(i - 1024 + 32) * 1024 + k];
    } else {
        v = 0.f;
    }
    Wcb[(size_t)dir * WCB_STR + idx] = f2bf(v);
}

// ---------------- MFMA GEMM (bf16): C (+)= alpha * [A|A2] @ W^T -------------
// CFG=0 (128x128/BK32): A DIRECT FROM GLOBAL into MFMA registers (prefetched
// one K-step ahead, afA/afB named sets); only W staged in LDS (2x8KB dbuf,
// one barrier/step). Halves LDS traffic per MFMA — the derived bottleneck
// (48KB/block-step at ~85 B/cy b128 rate matched the measured ~1.4-2kcy/step).
// CFG0 callers guarantee A2==A, K1==K.
// CFG=1 (64x64/BK64): unchanged R26 path (supports the [A|A2] K-split, GEMM3).
// cmode: 0 = fp32 store, 2 = bf16 store, 3 = GEMM2 epilogue. XCD swizzle.
template<int CFG>
__global__ __launch_bounds__(256)
void gemm_bf16(const short* __restrict__ A, const short* __restrict__ A2,
               int lda, int K1,
               const short* __restrict__ W, int ldw,
               void* __restrict__ Cv, int ldc,
               int K, float alpha, int cmode,
               const float* __restrict__ dtb0, const float* __restrict__ dtb1,
               float* __restrict__ BCb, int aStr, int wStr)
{
    constexpr int TMc = CFG ? 64 : 128;
    constexpr int TKc = CFG ? 64 : 32;
    constexpr int WTS = CFG ? 32 : 64;    // wave tile stride
    constexpr int FC  = CFG ? 2 : 4;      // frag count per dim

    // XCD swizzle (all grids have nwg % 8 == 0)
    const int nx = gridDim.x, ny = gridDim.y;
    const int nwg = nx * ny * gridDim.z;
    int lin = blockIdx.x + nx * (blockIdx.y + ny * blockIdx.z);
    int swz = (lin & 7) * (nwg >> 3) + (lin >> 3);
    const int bx = swz % nx;
    int tmp = swz / nx;
    const int by = tmp % ny;
    const int dir = tmp / ny;

    A  += (size_t)dir * aStr;
    A2 += (size_t)dir * aStr;
    W  += (size_t)dir * wStr;

    const int tid  = threadIdx.x;
    const int lane = tid & 63;
    const int wid  = tid >> 6;
    const int wr   = wid >> 1, wc = wid & 1;
    const int m0 = by * TMc;
    const int n0 = bx * TMc;

    f32x4 acc[FC][FC] = {};
    const int nt = K / TKc;

    if constexpr (CFG == 0) {
        __shared__ __align__(16) short Ws[2][TMc * TKc];   // W only, 2 x 8 KB

        // W staging map (chunk ci = nblk*64 + kc*16 + nl)
        const int am0 = ((tid >> 6) << 4) | (tid & 15);
        const int kc0 = (tid >> 4) & 3;
        const short* pw0 = W + (size_t)(n0 + am0) * ldw + kc0 * 8;
        const short* pw1 = pw0 + (size_t)64 * ldw;
        const int ci0 = tid, ci1 = tid + 256;

        // A-frag base: lane reads A[m0 + wr*64 + f*16 + (lane&15)][ (lane>>4)*8 + k ]
        const short* paf = A + (size_t)(m0 + wr * 64 + (lane & 15)) * lda
                             + ((lane >> 4) << 3);
        const size_t fstep = (size_t)16 * lda;

        bf16x8 rw0, rw1, afA[4], afB[4];

#define LOADW(tt) do { const int o_ = (tt) * TKc;                    \
        rw0 = *(const bf16x8*)(pw0 + o_);                            \
        rw1 = *(const bf16x8*)(pw1 + o_); } while (0)
#define WSTAGE(buf) do {                                             \
        *(bf16x8*)(Ws[buf] + ci0 * 8) = rw0;                         \
        *(bf16x8*)(Ws[buf] + ci1 * 8) = rw1; } while (0)
#define LOADAF(tt, dst) do { const int o_ = (tt) * TKc;              \
        dst[0] = *(const bf16x8*)(paf + o_);                         \
        dst[1] = *(const bf16x8*)(paf + fstep + o_);                 \
        dst[2] = *(const bf16x8*)(paf + 2 * fstep + o_);             \
        dst[3] = *(const bf16x8*)(paf + 3 * fstep + o_); } while (0)
#define COMPUTE(afX, buf) do {                                       \
        bf16x8 bff[4];                                               \
        _Pragma("unroll")                                            \
        for (int f = 0; f < 4; ++f) {                                \
            int bi = (wc * 4 + f) * 64 + (lane >> 4) * 16 + (lane & 15); \
            bff[f] = *(const bf16x8*)(&Ws[buf][bi * 8]);             \
        }                                                            \
        _Pragma("unroll")                                            \
        for (int i = 0; i < 4; ++i)                                  \
            _Pragma("unroll")                                        \
            for (int j = 0; j < 4; ++j)                              \
                acc[i][j] = __builtin_amdgcn_mfma_f32_16x16x32_bf16( \
                    afX[i], bff[j], acc[i][j], 0, 0, 0); } while (0)

        LOADW(0);
        WSTAGE(0);
        LOADW(1);
        LOADAF(0, afA);
        __syncthreads();

        for (int t = 0; t < nt; t += 2) {           // nt even (16 or 32)
            // sub-iter t (buf 0): stage W(t+1)->buf1, prefetch W(t+2), A(t+1)
            WSTAGE(1);
            if (t + 2 < nt) LOADW(t + 2);
            LOADAF(t + 1, afB);
            COMPUTE(afA, 0);
            __syncthreads();
            // sub-iter t+1 (buf 1)
            if (t + 2 < nt) {
                WSTAGE(0);
                if (t + 3 < nt) LOADW(t + 3);
                LOADAF(t + 2, afA);
            }
            COMPUTE(afB, 1);
            __syncthreads();
        }
#undef LOADW
#undef WSTAGE
#undef LOADAF
#undef COMPUTE
    } else {
        __shared__ __align__(16) short As[2][TMc * TKc];
        __shared__ __align__(16) short Ws[2][TMc * TKc];

        const int am0 = ((tid >> 7) << 4) | (tid & 15);
        const int kc0 = (tid >> 4) & 7;
        const int rstep = 32;
        const size_t arow0 = (size_t)(m0 + am0) * lda + kc0 * 8;
        const size_t arow1 = arow0 + (size_t)rstep * lda;
        const short* pw0 = W + (size_t)(n0 + am0) * ldw + kc0 * 8;
        const short* pw1 = pw0 + (size_t)rstep * ldw;
        const int ci0 = tid, ci1 = tid + 256;

        bf16x8 ra0, ra1, rw0, rw1;

#define LOADR(tt) do {                                          \
    const int off_ = (tt) * TKc;                                \
    const short* ab_ = (off_ < K1) ? A : A2;                    \
    const int ao_ = (off_ < K1) ? off_ : off_ - K1;             \
    ra0 = *(const bf16x8*)(ab_ + arow0 + ao_);                  \
    ra1 = *(const bf16x8*)(ab_ + arow1 + ao_);                  \
    rw0 = *(const bf16x8*)(pw0 + off_);                         \
    rw1 = *(const bf16x8*)(pw1 + off_); } while (0)

#define DSWRITE(buf) do {                                       \
    *(bf16x8*)(As[buf] + ci0 * 8) = ra0;                        \
    *(bf16x8*)(As[buf] + ci1 * 8) = ra1;                        \
    *(bf16x8*)(Ws[buf] + ci0 * 8) = rw0;                        \
    *(bf16x8*)(Ws[buf] + ci1 * 8) = rw1; } while (0)

        LOADR(0);
        DSWRITE(0);
        LOADR(1);
        __syncthreads();

        for (int t = 0; t < nt; ++t) {
            const int cur = t & 1;
            if (t + 1 < nt) DSWRITE(cur ^ 1);
            if (t + 2 < nt) LOADR(t + 2);

            bf16x8 af[2][2], bff[2][2];
#pragma unroll
            for (int f = 0; f < 2; ++f)
#pragma unroll
                for (int ks = 0; ks < 2; ++ks) {
                    int ai = (wr * 2 + f) * 128 + ks * 64 + (lane >> 4) * 16 + (lane & 15);
                    af[f][ks] = *(const bf16x8*)(&As[cur][ai * 8]);
                    int bi = (wc * 2 + f) * 128 + ks * 64 + (lane >> 4) * 16 + (lane & 15);
                    bff[f][ks] = *(const bf16x8*)(&Ws[cur][bi * 8]);
                }
#pragma unroll
            for (int i = 0; i < 2; ++i)
#pragma unroll
                for (int j = 0; j < 2; ++j) {
                    acc[i][j] = __builtin_amdgcn_mfma_f32_16x16x32_bf16(
                        af[i][0], bff[j][0], acc[i][j], 0, 0, 0);
                    acc[i][j] = __builtin_amdgcn_mfma_f32_16x16x32_bf16(
                        af[i][1], bff[j][1], acc[i][j], 0, 0, 0);
                }
            __syncthreads();
        }
#undef LOADR
#undef DSWRITE
    }

    if (cmode == 2) {
        short* C = (short*)Cv;
#pragma unroll
        for (int i = 0; i < FC; ++i) {
            int row = m0 + wr * WTS + i * 16 + ((lane >> 4) << 2);
#pragma unroll
            for (int j = 0; j < FC; ++j) {
                int col = n0 + wc * WTS + j * 16 + (lane & 15);
#pragma unroll
                for (int r = 0; r < 4; ++r)
                    C[(size_t)(row + r) * ldc + col] = f2bf(alpha * acc[i][j][r]);
            }
        }
    } else if (cmode == 3) {
        if (n0 < 1024) {
            short* dtO = (short*)Cv;   // xzb base
            const float* dtb = dir ? dtb1 : dtb0;
#pragma unroll
            for (int i = 0; i < FC; ++i) {
                int row = m0 + wr * WTS + i * 16 + ((lane >> 4) << 2);
#pragma unroll
                for (int j = 0; j < FC; ++j) {
                    int col = n0 + wc * WTS + j * 16 + (lane & 15);
                    float bias = dtb[col];
#pragma unroll
                    for (int r = 0; r < 4; ++r) {
                        float v = softplus_fast(acc[i][j][r] + bias);
                        dtO[(size_t)(row + r) * 4096 + dir * 2048 + col] = f2bf(v);
                    }
                }
            }
        } else {
            float* bc = BCb + (size_t)dir * BC_STR;
#pragma unroll
            for (int i = 0; i < FC; ++i) {
                int row = m0 + wr * WTS + i * 16 + ((lane >> 4) << 2);
#pragma unroll
                for (int j = 0; j < FC; ++j) {
                    int col = n0 + wc * WTS + j * 16 + (lane & 15);
                    if (col < 1056) {
#pragma unroll
                        for (int r = 0; r < 4; ++r)
                            bc[(size_t)(row + r) * 32 + (col - 1024)] = acc[i][j][r];
                    }
                }
            }
        }
    } else {
        float* C = (float*)Cv;
#pragma unroll
        for (int i = 0; i < FC; ++i) {
            int row = m0 + wr * WTS + i * 16 + ((lane >> 4) << 2);
#pragma unroll
            for (int j = 0; j < FC; ++j) {
                int col = n0 + wc * WTS + j * 16 + (lane & 15);
#pragma unroll
                for (int r = 0; r < 4; ++r)
                    C[(size_t)(row + r) * ldc + col] = alpha * acc[i][j][r];
            }
        }
    }
}

// ---------------- depthwise conv (k=4) + bias + SiLU, both dirs -----------
__global__ __launch_bounds__(256)
void conv_silu_kernel(const short* __restrict__ xzb,
                      const float* __restrict__ cw0, const float* __restrict__ cw1,
                      const float* __restrict__ cb0, const float* __restrict__ cb1,
                      short* __restrict__ xcb)
{
    const int rev = blockIdx.y;
    int idx = blockIdx.x * 256 + threadIdx.x;
    if (idx >= NTOK * D_INNER) return;
    int c   = idx & (D_INNER - 1);
    int row = idx >> 10;
    int b   = row / SEQ;
    int u   = row - b * SEQ;
    const int coff = rev * 2048 + c;
    const float* cw = rev ? cw1 : cw0;
    const float* cb = rev ? cb1 : cb0;

    float w0 = cw[c * 4 + 0], w1 = cw[c * 4 + 1];
    float w2 = cw[c * 4 + 2], w3 = cw[c * 4 + 3];
    float accv = cb[c];
    if (!rev) {
#pragma unroll
        for (int k = 0; k < 4; ++k) {
            int uu = u - 3 + k;
            float wv = (k == 0) ? w0 : (k == 1) ? w1 : (k == 2) ? w2 : w3;
            if (uu >= 0)
                accv = fmaf(wv, bf2f(xzb[(size_t)(b * SEQ + uu) * 4096 + coff]), accv);
        }
    } else {
#pragma unroll
        for (int k = 0; k < 4; ++k) {
            int uu = u + 3 - k;
            float wv = (k == 0) ? w0 : (k == 1) ? w1 : (k == 2) ? w2 : w3;
            if (uu < SEQ)
                accv = fmaf(wv, bf2f(xzb[(size_t)(b * SEQ + uu) * 4096 + coff]), accv);
        }
    }
    float r = accv / (1.f + __expf(-accv));
    xcb[(size_t)rev * XCB_STR + idx] = f2bf(r);
}

// ---------------- chunked SSM scan, both dirs, CHUNK=64 -------------------
__global__ __launch_bounds__(256)
void scan_p1(const short* __restrict__ xzb,
             const short* __restrict__ xcb,
             const float* __restrict__ BCb,
             const float* __restrict__ A_log0, const float* __restrict__ A_log1,
             float* __restrict__ chP, float* __restrict__ chH)
{
    __shared__ float Bs[CHUNK][16];
    const int tid = threadIdx.x;
    const int blk = blockIdx.x;
    const int dir = blk >> 8;
    const int rr  = blk & 255;
    const int cb = rr & 3;
    const int ch = (rr >> 2) & (NCH - 1);
    const int b  = rr >> 7;
    const int c  = cb * 256 + tid;
    const int rev = dir;

    const int u0 = rev ? (SEQ - 1 - ch * CHUNK) : (ch * CHUNK);
    const int st = rev ? -1 : 1;
    const float* A_log = dir ? A_log1 : A_log0;
    const float* bcD = BCb + (size_t)dir * BC_STR;

    for (int r = tid; r < CHUNK * 16; r += 256) {
        int i = r >> 4, s = r & 15;
        int row = b * SEQ + u0 + st * i;
        Bs[i][s] = bcD[(size_t)row * 32 + s];
    }

    float Acs[16];
#pragma unroll
    for (int s = 0; s < 16; ++s)
        Acs[s] = -__expf(A_log[c * 16 + s]) * 1.44269504f;

    float h[16];
    float dts = 0.f;   // P[s] = exp2(Acs[s] * sum(dt))
#pragma unroll
    for (int s = 0; s < 16; ++s) h[s] = 0.f;

    __syncthreads();

    const short* dtp = xzb + (size_t)(b * SEQ + u0) * 4096 + dir * 2048 + c;
    const short* xcp = xcb + (size_t)dir * XCB_STR + (size_t)(b * SEQ + u0) * D_INNER + c;
    const ptrdiff_t dstep = (ptrdiff_t)st * 4096;
    const ptrdiff_t xstep = (ptrdiff_t)st * D_INNER;

    float dt_r[PG], xc_r[PG];
#pragma unroll
    for (int j = 0; j < PG; ++j) {
        dt_r[j] = bf2f(dtp[dstep * j]);
        xc_r[j] = bf2f(xcp[xstep * j]);
    }

#pragma unroll 1
    for (int g = 0; g < NPG; ++g) {
        const int gg = (g + 1 < NPG) ? (g + 1) : g;
        float dt_n[PG], xc_n[PG];
#pragma unroll
        for (int j = 0; j < PG; ++j) {
            int i = gg * PG + j;
            dt_n[j] = bf2f(dtp[dstep * i]);
            xc_n[j] = bf2f(xcp[xstep * i]);
        }
#pragma unroll
        for (int j = 0; j < PG; ++j) {
            int i = g * PG + j;
            float dtv = dt_r[j];
            float e = dtv * xc_r[j];
            dts += dtv;
#pragma unroll
            for (int s = 0; s < 16; ++s) {
                float da = __builtin_amdgcn_exp2f(dtv * Acs[s]);
                h[s] = fmaf(da, h[s], e * Bs[i][s]);
            }
        }
#pragma unroll
        for (int j = 0; j < PG; ++j) { dt_r[j] = dt_n[j]; xc_r[j] = xc_n[j]; }
    }

    size_t o = (size_t)dir * CH_STR + ((size_t)(b * NCH + ch) * 1024 + c) * 16;
#pragma unroll
    for (int q = 0; q < 4; ++q) {
        float4 pv;
        pv.x = __builtin_amdgcn_exp2f(Acs[q*4+0] * dts);
        pv.y = __builtin_amdgcn_exp2f(Acs[q*4+1] * dts);
        pv.z = __builtin_amdgcn_exp2f(Acs[q*4+2] * dts);
        pv.w = __builtin_amdgcn_exp2f(Acs[q*4+3] * dts);
        *(float4*)&chP[o + q * 4] = pv;
        *(float4*)&chH[o + q * 4] = make_float4(h[q*4], h[q*4+1], h[q*4+2], h[q*4+3]);
    }
}

__global__ __launch_bounds__(256)
void scan_p2(float* __restrict__ chPH, const float* __restrict__ chH)
{
    int idx = blockIdx.x * 256 + threadIdx.x;   // [0, 2*B_SZ*16384)
    int dir = idx >> 15;
    int rem = idx & 32767;
    int b  = rem >> 14;
    int cs = rem & 16383;
    size_t base = (size_t)dir * CH_STR;
    float h = 0.f;
#pragma unroll
    for (int ch = 0; ch < NCH; ++ch) {
        size_t o = base + ((size_t)(b * NCH + ch) << 14) + cs;
        float Pv = chPH[o], Hv = chH[o];
        chPH[o] = h;
        h = fmaf(Pv, h, Hv);
    }
}

__global__ __launch_bounds__(256)
void scan_p3(const short* __restrict__ xzb,
             short* __restrict__ xcb,           // xc in, ybar out (in place)
             const float* __restrict__ BCb,
             const float* __restrict__ A_log0, const float* __restrict__ A_log1,
             const float* __restrict__ Dp0, const float* __restrict__ Dp1,
             const float* __restrict__ hst)
{
    __shared__ float Bs[CHUNK][16];
    __shared__ float Cs[CHUNK][16];
    const int tid = threadIdx.x;
    const int blk = blockIdx.x;
    const int dir = blk >> 8;
    const int rr  = blk & 255;
    const int cb = rr & 3;
    const int ch = (rr >> 2) & (NCH - 1);
    const int b  = rr >> 7;
    const int c  = cb * 256 + tid;
    const int rev = dir;

    const int u0 = rev ? (SEQ - 1 - ch * CHUNK) : (ch * CHUNK);
    const int st = rev ? -1 : 1;
    const float* A_log = dir ? A_log1 : A_log0;
    const float* Dp    = dir ? Dp1 : Dp0;
    const float* bcD = BCb + (size_t)dir * BC_STR;

    for (int r = tid; r < CHUNK * 16; r += 256) {
        int i = r >> 4, s = r & 15;
        int row = b * SEQ + u0 + st * i;
        Bs[i][s] = bcD[(size_t)row * 32 + s];
        Cs[i][s] = bcD[(size_t)row * 32 + 16 + s];
    }

    float Acs[16];
#pragma unroll
    for (int s = 0; s < 16; ++s)
        Acs[s] = -__expf(A_log[c * 16 + s]) * 1.44269504f;

    const float Dc = Dp[c];

    float h[16];
    size_t o = (size_t)dir * CH_STR + ((size_t)(b * NCH + ch) * 1024 + c) * 16;
#pragma unroll
    for (int q = 0; q < 4; ++q) {
        float4 hv = *(const float4*)&hst[o + q * 4];
        h[q*4] = hv.x; h[q*4+1] = hv.y; h[q*4+2] = hv.z; h[q*4+3] = hv.w;
    }

    __syncthreads();

    const short* dtp = xzb + (size_t)(b * SEQ + u0) * 4096 + dir * 2048 + c;
    const short* zp  = xzb + (size_t)(b * SEQ + u0) * 4096 + dir * 2048 + 1024 + c;
    short*       xcp = xcb + (size_t)dir * XCB_STR + (size_t)(b * SEQ + u0) * D_INNER + c;
    const ptrdiff_t dstep = (ptrdiff_t)st * 4096;
    const ptrdiff_t xstep = (ptrdiff_t)st * D_INNER;

    float dt_r[PG], xc_r[PG], z_r[PG];
#pragma unroll
    for (int j = 0; j < PG; ++j) {
        dt_r[j] = bf2f(dtp[dstep * j]);
        xc_r[j] = bf2f(xcp[xstep * j]);
        z_r[j]  = bf2f(zp[dstep * j]);
    }

#pragma unroll 1
    for (int g = 0; g < NPG; ++g) {
        const int gg = (g + 1 < NPG) ? (g + 1) : g;
        float dt_n[PG], xc_n[PG], z_n[PG];
#pragma unroll
        for (int j = 0; j < PG; ++j) {
            int i = gg * PG + j;
            dt_n[j] = bf2f(dtp[dstep * i]);
            xc_n[j] = bf2f(xcp[xstep * i]);
            z_n[j]  = bf2f(zp[dstep * i]);
        }
#pragma unroll
        for (int j = 0; j < PG; ++j) {
            int i = g * PG + j;
            float dtv = dt_r[j];
            float xcv = xc_r[j];
            float e = dtv * xcv;
            float y = 0.f;
#pragma unroll
            for (int s = 0; s < 16; ++s) {
                float da = __builtin_amdgcn_exp2f(dtv * Acs[s]);
                h[s] = fmaf(da, h[s], e * Bs[i][s]);
                y = fmaf(h[s], Cs[i][s], y);
            }
            y = fmaf(Dc, xcv, y);
            float zv = z_r[j];
            float sig = 1.f / (1.f + __expf(-zv));
            xcp[xstep * i] = f2bf(y * zv * sig);   // ybar in place
        }
#pragma unroll
        for (int j = 0; j < PG; ++j) {
            dt_r[j] = dt_n[j]; xc_r[j] = xc_n[j]; z_r[j] = z_n[j];
        }
    }
}

extern "C" void kernel_launch(void* const* d_in, const int* in_sizes, int n_in,
                              void* d_out, int out_size, void* d_ws, size_t ws_size,
                              hipStream_t stream)
{
    const float* x = (const float*)d_in[0];
    float* out = (float*)d_out;
    float* ws  = (float*)d_ws;

    // workspace: 20,840,448 floats = 83.36 MB (< proven 92.27 MB)
    short* xzb  = (short*)ws;                    // [4096][4096] bf16  (8,388,608 fl)
    float* BCb  = ws + 8388608;                  // [2][4096][32] f32  (262,144 fl)
    float* chP  = ws + 8650752;                  // [2][CH_STR]        (2,097,152 fl)
    float* chH  = ws + 10747904;                 // [2][CH_STR]        (2,097,152 fl)
    short* Wcb  = (short*)(ws + 12845056);       // [2][1152][1024]    (1,179,648 fl)
    short* xbf  = (short*)(ws + 14024704);       // [4096][512] bf16   (1,048,576 fl)
    short* W1b  = (short*)(ws + 15073280);       // [4096][512] bf16   (1,048,576 fl)
    short* Wcat = (short*)(ws + 16121856);       // [512][2048] bf16   (524,288 fl)
    short* xcb  = (short*)(ws + 16646144);       // [2][4096][1024]    (4,194,304 fl)

    const int gElem = (NTOK * D_INNER + 255) / 256;

    // ---- shared prep ----
    cvt_bf16<<<(NTOK * DIM / 8 + 255) / 256, 256, 0, stream>>>(x, xbf, NTOK * DIM);
    cvt_bf16<<<(2 * D_INNER * DIM / 8 + 255) / 256, 256, 0, stream>>>(
        (const float*)d_in[1 + 0 * 9 + 0], W1b, 2 * D_INNER * DIM);
    cvt_bf16<<<(2 * D_INNER * DIM / 8 + 255) / 256, 256, 0, stream>>>(
        (const float*)d_in[1 + 1 * 9 + 0], W1b + 2 * D_INNER * DIM, 2 * D_INNER * DIM);
    cvt_wcat<<<(512 * 2048 + 255) / 256, 256, 0, stream>>>(
        (const float*)d_in[1 + 0 * 9 + 8], (const float*)d_in[1 + 1 * 9 + 8], Wcat);
    {
        dim3 g((NC_PAD * D_INNER + 255) / 256, 2);
        build_wc<<<g, 256, 0, stream>>>(
            (const float*)d_in[1 + 0 * 9 + 3], (const float*)d_in[1 + 1 * 9 + 3],
            (const float*)d_in[1 + 0 * 9 + 4], (const float*)d_in[1 + 1 * 9 + 4],
            Wcb);
    }

    // GEMM1: xzb = x @ [in_w_f; in_w_r]^T  [4096,4096] bf16, grid 32x32
    {
        dim3 g(4096 / 128, NTOK / 128, 1);
        gemm_bf16<0><<<g, 256, 0, stream>>>(xbf, xbf, DIM, DIM, W1b, DIM,
                                            xzb, 4096, DIM, 1.f, 2,
                                            nullptr, nullptr, nullptr, 0, 0);
    }
    // conv+SiLU both dirs -> xcb
    {
        dim3 g(gElem, 2);
        conv_silu_kernel<<<g, 256, 0, stream>>>(
            xzb,
            (const float*)d_in[1 + 0 * 9 + 1], (const float*)d_in[1 + 1 * 9 + 1],
            (const float*)d_in[1 + 0 * 9 + 2], (const float*)d_in[1 + 1 * 9 + 2],
            xcb);
    }
    // GEMM2 both dirs (fused fast softplus; dt->xzb xi-cols bf16, BC->BCb)
    {
        dim3 g(NC_PAD / 128, NTOK / 128, 2);   // 9 x 32 x 2 = 576 blocks
        gemm_bf16<0><<<g, 256, 0, stream>>>(xcb, xcb, D_INNER, D_INNER,
                                            Wcb, D_INNER,
                                            xzb, 0, D_INNER, 1.f, 3,
                                            (const float*)d_in[1 + 0 * 9 + 5],
                                            (const float*)d_in[1 + 1 * 9 + 5],
                                            BCb, XCB_STR, WCB_STR);
    }
    // scans, both dirs — CHUNK=64, 512 blocks
    scan_p1<<<512, 256, 0, stream>>>(xzb, xcb, BCb,
                                     (const float*)d_in[1 + 0 * 9 + 6],
                                     (const float*)d_in[1 + 1 * 9 + 6],
                                     chP, chH);
    scan_p2<<<(2 * B_SZ * 16384) / 256, 256, 0, stream>>>(chP, chH);
    scan_p3<<<512, 256, 0, stream>>>(xzb, xcb, BCb,
                                     (const float*)d_in[1 + 0 * 9 + 6],
                                     (const float*)d_in[1 + 1 * 9 + 6],
                                     (const float*)d_in[1 + 0 * 9 + 7],
                                     (const float*)d_in[1 + 1 * 9 + 7],
                                     chP);
    // GEMM3: out = 0.5 * [ybar_f | ybar_r] @ Wcat^T, K=2048 — 64^2 tile
    {
        dim3 g(DIM / 64, NTOK / 64, 1);
        gemm_bf16<1><<<g, 256, 0, stream>>>(xcb, xcb + XCB_STR, D_INNER, D_INNER,
                                            Wcat, 2 * D_INNER,
                                            out, DIM, 2 * D_INNER, 0.5f, 0,
                                            nullptr, nullptr, nullptr, 0, 0);
    }
}

// Round 31
// 253.843 us; speedup vs baseline: 1.1473x; 1.1473x over previous
//
#include <hip/hip_runtime.h>
#include <hip/hip_bf16.h>
#include <math.h>

#define DIM      512
#define D_STATE  16
#define D_CONV   4
#define D_INNER  1024
#define DT_RANK  32
#define B_SZ     2
#define SEQ      2048
#define NTOK     (B_SZ * SEQ)   // 4096
#define CHUNK    64
#define NCH      (SEQ / CHUNK)  // 32
#define NC_PAD   1152
#define PG       8
#define NPG      (CHUNK / PG)   // 8

// strides (elements)
#define XCB_STR   4194304   // [4096][1024] bf16 per dir (shorts)
#define WCB_STR   1179648   // [1152][1024] bf16 per dir (shorts)
#define BC_STR    131072    // [4096][32] fp32 per dir (floats)
#define CH_STR    1048576   // B_SZ*NCH*1024*16 fp32 per dir (floats)

typedef __attribute__((ext_vector_type(8))) short bf16x8;
typedef __attribute__((ext_vector_type(4))) float f32x4;

__device__ __forceinline__ short f2bf(float f) {
    unsigned u = __float_as_uint(f);
    u += 0x7fffu + ((u >> 16) & 1u);
    return (short)(u >> 16);
}
__device__ __forceinline__ float bf2f(short v) {
    return __uint_as_float(((unsigned)(unsigned short)v) << 16);
}
__device__ __forceinline__ float softplus_fast(float v) {
    return (v > 20.f) ? v : __logf(1.f + __expf(v));
}

// ---------------- fp32 -> bf16 bulk convert (n % 8 == 0) ------------------
__global__ __launch_bounds__(256)
void cvt_bf16(const float* __restrict__ src, short* __restrict__ dst, int n)
{
    int i = (blockIdx.x * 256 + threadIdx.x) * 8;
    if (i >= n) return;
    float4 a = *(const float4*)(src + i);
    float4 b = *(const float4*)(src + i + 4);
    bf16x8 v;
    v[0] = f2bf(a.x); v[1] = f2bf(a.y); v[2] = f2bf(a.z); v[3] = f2bf(a.w);
    v[4] = f2bf(b.x); v[5] = f2bf(b.y); v[6] = f2bf(b.z); v[7] = f2bf(b.w);
    *(bf16x8*)(dst + i) = v;
}

// Wcat[512][2048] = [out_w_f | out_w_r] along K (bf16)
__global__ __launch_bounds__(256)
void cvt_wcat(const float* __restrict__ wf, const float* __restrict__ wr,
              short* __restrict__ Wcat)
{
    int idx = blockIdx.x * 256 + threadIdx.x;
    if (idx >= 512 * 2048) return;
    int n = idx >> 11, col = idx & 2047;
    const float* src = (col < 1024) ? wf : wr;
    Wcat[idx] = f2bf(src[n * 1024 + (col & 1023)]);
}

// ---------------- combined projection weight, both dirs ------------------
__global__ __launch_bounds__(256)
void build_wc(const float* __restrict__ xp0, const float* __restrict__ xp1,
              const float* __restrict__ dw0, const float* __restrict__ dw1,
              short* __restrict__ Wcb)
{
    const int dir = blockIdx.y;
    int idx = blockIdx.x * 256 + threadIdx.x;
    if (idx >= NC_PAD * D_INNER) return;
    const float* xproj_w = dir ? xp1 : xp0;
    const float* dt_w    = dir ? dw1 : dw0;
    int i = idx >> 10, k = idx & 1023;
    float v;
    if (i < 1024) {
        v = 0.f;
#pragma unroll
        for (int r = 0; r < 32; ++r)
            v = fmaf(dt_w[i * 32 + r], xproj_w[r * 1024 + k], v);
    } else if (i < 1056) {
        v = xproj_w[(i - 1024 + 32) * 1024 + k];
    } else {
        v = 0.f;
    }
    Wcb[(size_t)dir * WCB_STR + idx] = f2bf(v);
}

// ---------------- MFMA GEMM (bf16): C (+)= alpha * [A|A2] @ W^T -------------
// Templated tile config. CFG=0: 128x128/BK32 (4x4 frags/wave). CFG=1:
// 64x64/BK64 (2x2 frags x 2 k-subtiles) for grid-starved shapes (GEMM3).
// Both: reg-staged (1-deep) + LDS double buffer, ONE barrier per K-step.
// Fast hw transcendentals in cmode-3 epilogue. XCD swizzle.
// cmode: 0 = fp32 store, 2 = bf16 store, 3 = GEMM2 epilogue.
template<int CFG>
__global__ __launch_bounds__(256)
void gemm_bf16(const short* __restrict__ A, const short* __restrict__ A2,
               int lda, int K1,
               const short* __restrict__ W, int ldw,
               void* __restrict__ Cv, int ldc,
               int K, float alpha, int cmode,
               const float* __restrict__ dtb0, const float* __restrict__ dtb1,
               float* __restrict__ BCb, int aStr, int wStr)
{
    constexpr int TMc = CFG ? 64 : 128;
    constexpr int TKc = CFG ? 64 : 32;
    constexpr int WTS = CFG ? 32 : 64;    // wave tile stride
    constexpr int FC  = CFG ? 2 : 4;      // frag count per dim
    __shared__ __align__(16) short As[2][TMc * TKc];   // 2 x 8 KB
    __shared__ __align__(16) short Ws[2][TMc * TKc];

    // XCD swizzle (all grids have nwg % 8 == 0)
    const int nx = gridDim.x, ny = gridDim.y;
    const int nwg = nx * ny * gridDim.z;
    int lin = blockIdx.x + nx * (blockIdx.y + ny * blockIdx.z);
    int swz = (lin & 7) * (nwg >> 3) + (lin >> 3);
    const int bx = swz % nx;
    int tmp = swz / nx;
    const int by = tmp % ny;
    const int dir = tmp / ny;

    A  += (size_t)dir * aStr;
    A2 += (size_t)dir * aStr;
    W  += (size_t)dir * wStr;

    const int tid  = threadIdx.x;
    const int lane = tid & 63;
    const int wid  = tid >> 6;
    const int wr   = wid >> 1, wc = wid & 1;
    const int m0 = by * TMc;
    const int n0 = bx * TMc;

    const int am0 = CFG ? (((tid >> 7) << 4) | (tid & 15))
                        : (((tid >> 6) << 4) | (tid & 15));
    const int kc0 = CFG ? ((tid >> 4) & 7) : ((tid >> 4) & 3);
    const int rstep = CFG ? 32 : 64;
    const size_t arow0 = (size_t)(m0 + am0) * lda + kc0 * 8;
    const size_t arow1 = arow0 + (size_t)rstep * lda;
    const short* pw0 = W + (size_t)(n0 + am0) * ldw + kc0 * 8;
    const short* pw1 = pw0 + (size_t)rstep * ldw;

    const int ci0 = tid, ci1 = tid + 256;

    f32x4 acc[FC][FC] = {};
    const int nt = K / TKc;

    bf16x8 ra0, ra1, rw0, rw1;

#define LOADR(tt) do {                                          \
    const int off_ = (tt) * TKc;                                \
    const short* ab_ = (off_ < K1) ? A : A2;                    \
    const int ao_ = (off_ < K1) ? off_ : off_ - K1;             \
    ra0 = *(const bf16x8*)(ab_ + arow0 + ao_);                  \
    ra1 = *(const bf16x8*)(ab_ + arow1 + ao_);                  \
    rw0 = *(const bf16x8*)(pw0 + off_);                         \
    rw1 = *(const bf16x8*)(pw1 + off_); } while (0)

#define DSWRITE(buf) do {                                       \
    *(bf16x8*)(As[buf] + ci0 * 8) = ra0;                        \
    *(bf16x8*)(As[buf] + ci1 * 8) = ra1;                        \
    *(bf16x8*)(Ws[buf] + ci0 * 8) = rw0;                        \
    *(bf16x8*)(Ws[buf] + ci1 * 8) = rw1; } while (0)

    LOADR(0);
    DSWRITE(0);
    LOADR(1);
    __syncthreads();

    for (int t = 0; t < nt; ++t) {
        const int cur = t & 1;
        if (t + 1 < nt) DSWRITE(cur ^ 1);
        if (t + 2 < nt) LOADR(t + 2);

        if constexpr (CFG == 0) {
            bf16x8 af[4], bff[4];
#pragma unroll
            for (int f = 0; f < 4; ++f) {
                int ai = (wr * 4 + f) * 64 + (lane >> 4) * 16 + (lane & 15);
                af[f]  = *(const bf16x8*)(&As[cur][ai * 8]);
                int bi = (wc * 4 + f) * 64 + (lane >> 4) * 16 + (lane & 15);
                bff[f] = *(const bf16x8*)(&Ws[cur][bi * 8]);
            }
#pragma unroll
            for (int i = 0; i < 4; ++i)
#pragma unroll
                for (int j = 0; j < 4; ++j)
                    acc[i][j] = __builtin_amdgcn_mfma_f32_16x16x32_bf16(
                        af[i], bff[j], acc[i][j], 0, 0, 0);
        } else {
            bf16x8 af[2][2], bff[2][2];
#pragma unroll
            for (int f = 0; f < 2; ++f)
#pragma unroll
                for (int ks = 0; ks < 2; ++ks) {
                    int ai = (wr * 2 + f) * 128 + ks * 64 + (lane >> 4) * 16 + (lane & 15);
                    af[f][ks] = *(const bf16x8*)(&As[cur][ai * 8]);
                    int bi = (wc * 2 + f) * 128 + ks * 64 + (lane >> 4) * 16 + (lane & 15);
                    bff[f][ks] = *(const bf16x8*)(&Ws[cur][bi * 8]);
                }
#pragma unroll
            for (int i = 0; i < 2; ++i)
#pragma unroll
                for (int j = 0; j < 2; ++j) {
                    acc[i][j] = __builtin_amdgcn_mfma_f32_16x16x32_bf16(
                        af[i][0], bff[j][0], acc[i][j], 0, 0, 0);
                    acc[i][j] = __builtin_amdgcn_mfma_f32_16x16x32_bf16(
                        af[i][1], bff[j][1], acc[i][j], 0, 0, 0);
                }
        }
        __syncthreads();
    }
#undef LOADR
#undef DSWRITE

    if (cmode == 2) {
        short* C = (short*)Cv;
#pragma unroll
        for (int i = 0; i < FC; ++i) {
            int row = m0 + wr * WTS + i * 16 + ((lane >> 4) << 2);
#pragma unroll
            for (int j = 0; j < FC; ++j) {
                int col = n0 + wc * WTS + j * 16 + (lane & 15);
#pragma unroll
                for (int r = 0; r < 4; ++r)
                    C[(size_t)(row + r) * ldc + col] = f2bf(alpha * acc[i][j][r]);
            }
        }
    } else if (cmode == 3) {
        if (n0 < 1024) {
            short* dtO = (short*)Cv;   // xzb base
            const float* dtb = dir ? dtb1 : dtb0;
#pragma unroll
            for (int i = 0; i < FC; ++i) {
                int row = m0 + wr * WTS + i * 16 + ((lane >> 4) << 2);
#pragma unroll
                for (int j = 0; j < FC; ++j) {
                    int col = n0 + wc * WTS + j * 16 + (lane & 15);
                    float bias = dtb[col];
#pragma unroll
                    for (int r = 0; r < 4; ++r) {
                        float v = softplus_fast(acc[i][j][r] + bias);
                        dtO[(size_t)(row + r) * 4096 + dir * 2048 + col] = f2bf(v);
                    }
                }
            }
        } else {
            float* bc = BCb + (size_t)dir * BC_STR;
#pragma unroll
            for (int i = 0; i < FC; ++i) {
                int row = m0 + wr * WTS + i * 16 + ((lane >> 4) << 2);
#pragma unroll
                for (int j = 0; j < FC; ++j) {
                    int col = n0 + wc * WTS + j * 16 + (lane & 15);
                    if (col < 1056) {
#pragma unroll
                        for (int r = 0; r < 4; ++r)
                            bc[(size_t)(row + r) * 32 + (col - 1024)] = acc[i][j][r];
                    }
                }
            }
        }
    } else {
        float* C = (float*)Cv;
#pragma unroll
        for (int i = 0; i < FC; ++i) {
            int row = m0 + wr * WTS + i * 16 + ((lane >> 4) << 2);
#pragma unroll
            for (int j = 0; j < FC; ++j) {
                int col = n0 + wc * WTS + j * 16 + (lane & 15);
#pragma unroll
                for (int r = 0; r < 4; ++r)
                    C[(size_t)(row + r) * ldc + col] = alpha * acc[i][j][r];
            }
        }
    }
}

// ---------------- depthwise conv (k=4) + bias + SiLU, both dirs -----------
__global__ __launch_bounds__(256)
void conv_silu_kernel(const short* __restrict__ xzb,
                      const float* __restrict__ cw0, const float* __restrict__ cw1,
                      const float* __restrict__ cb0, const float* __restrict__ cb1,
                      short* __restrict__ xcb)
{
    const int rev = blockIdx.y;
    int idx = blockIdx.x * 256 + threadIdx.x;
    if (idx >= NTOK * D_INNER) return;
    int c   = idx & (D_INNER - 1);
    int row = idx >> 10;
    int b   = row / SEQ;
    int u   = row - b * SEQ;
    const int coff = rev * 2048 + c;
    const float* cw = rev ? cw1 : cw0;
    const float* cb = rev ? cb1 : cb0;

    float w0 = cw[c * 4 + 0], w1 = cw[c * 4 + 1];
    float w2 = cw[c * 4 + 2], w3 = cw[c * 4 + 3];
    float accv = cb[c];
    if (!rev) {
#pragma unroll
        for (int k = 0; k < 4; ++k) {
            int uu = u - 3 + k;
            float wv = (k == 0) ? w0 : (k == 1) ? w1 : (k == 2) ? w2 : w3;
            if (uu >= 0)
                accv = fmaf(wv, bf2f(xzb[(size_t)(b * SEQ + uu) * 4096 + coff]), accv);
        }
    } else {
#pragma unroll
        for (int k = 0; k < 4; ++k) {
            int uu = u + 3 - k;
            float wv = (k == 0) ? w0 : (k == 1) ? w1 : (k == 2) ? w2 : w3;
            if (uu < SEQ)
                accv = fmaf(wv, bf2f(xzb[(size_t)(b * SEQ + uu) * 4096 + coff]), accv);
        }
    }
    float r = accv / (1.f + __expf(-accv));
    xcb[(size_t)rev * XCB_STR + idx] = f2bf(r);
}

// ---------------- chunked SSM scan, both dirs, CHUNK=64 -------------------
__global__ __launch_bounds__(256)
void scan_p1(const short* __restrict__ xzb,
             const short* __restrict__ xcb,
             const float* __restrict__ BCb,
             const float* __restrict__ A_log0, const float* __restrict__ A_log1,
             float* __restrict__ chP, float* __restrict__ chH)
{
    __shared__ float Bs[CHUNK][16];
    const int tid = threadIdx.x;
    const int blk = blockIdx.x;
    const int dir = blk >> 8;
    const int rr  = blk & 255;
    const int cb = rr & 3;
    const int ch = (rr >> 2) & (NCH - 1);
    const int b  = rr >> 7;
    const int c  = cb * 256 + tid;
    const int rev = dir;

    const int u0 = rev ? (SEQ - 1 - ch * CHUNK) : (ch * CHUNK);
    const int st = rev ? -1 : 1;
    const float* A_log = dir ? A_log1 : A_log0;
    const float* bcD = BCb + (size_t)dir * BC_STR;

    for (int r = tid; r < CHUNK * 16; r += 256) {
        int i = r >> 4, s = r & 15;
        int row = b * SEQ + u0 + st * i;
        Bs[i][s] = bcD[(size_t)row * 32 + s];
    }

    float Acs[16];
#pragma unroll
    for (int s = 0; s < 16; ++s)
        Acs[s] = -__expf(A_log[c * 16 + s]) * 1.44269504f;

    float h[16];
    float dts = 0.f;   // P[s] = exp2(Acs[s] * sum(dt))
#pragma unroll
    for (int s = 0; s < 16; ++s) h[s] = 0.f;

    __syncthreads();

    const short* dtp = xzb + (size_t)(b * SEQ + u0) * 4096 + dir * 2048 + c;
    const short* xcp = xcb + (size_t)dir * XCB_STR + (size_t)(b * SEQ + u0) * D_INNER + c;
    const ptrdiff_t dstep = (ptrdiff_t)st * 4096;
    const ptrdiff_t xstep = (ptrdiff_t)st * D_INNER;

    float dt_r[PG], xc_r[PG];
#pragma unroll
    for (int j = 0; j < PG; ++j) {
        dt_r[j] = bf2f(dtp[dstep * j]);
        xc_r[j] = bf2f(xcp[xstep * j]);
    }

#pragma unroll 1
    for (int g = 0; g < NPG; ++g) {
        const int gg = (g + 1 < NPG) ? (g + 1) : g;
        float dt_n[PG], xc_n[PG];
#pragma unroll
        for (int j = 0; j < PG; ++j) {
            int i = gg * PG + j;
            dt_n[j] = bf2f(dtp[dstep * i]);
            xc_n[j] = bf2f(xcp[xstep * i]);
        }
#pragma unroll
        for (int j = 0; j < PG; ++j) {
            int i = g * PG + j;
            float dtv = dt_r[j];
            float e = dtv * xc_r[j];
            dts += dtv;
#pragma unroll
            for (int s = 0; s < 16; ++s) {
                float da = __builtin_amdgcn_exp2f(dtv * Acs[s]);
                h[s] = fmaf(da, h[s], e * Bs[i][s]);
            }
        }
#pragma unroll
        for (int j = 0; j < PG; ++j) { dt_r[j] = dt_n[j]; xc_r[j] = xc_n[j]; }
    }

    size_t o = (size_t)dir * CH_STR + ((size_t)(b * NCH + ch) * 1024 + c) * 16;
#pragma unroll
    for (int q = 0; q < 4; ++q) {
        float4 pv;
        pv.x = __builtin_amdgcn_exp2f(Acs[q*4+0] * dts);
        pv.y = __builtin_amdgcn_exp2f(Acs[q*4+1] * dts);
        pv.z = __builtin_amdgcn_exp2f(Acs[q*4+2] * dts);
        pv.w = __builtin_amdgcn_exp2f(Acs[q*4+3] * dts);
        *(float4*)&chP[o + q * 4] = pv;
        *(float4*)&chH[o + q * 4] = make_float4(h[q*4], h[q*4+1], h[q*4+2], h[q*4+3]);
    }
}

__global__ __launch_bounds__(256)
void scan_p2(float* __restrict__ chPH, const float* __restrict__ chH)
{
    int idx = blockIdx.x * 256 + threadIdx.x;   // [0, 2*B_SZ*16384)
    int dir = idx >> 15;
    int rem = idx & 32767;
    int b  = rem >> 14;
    int cs = rem & 16383;
    size_t base = (size_t)dir * CH_STR;
    float h = 0.f;
#pragma unroll
    for (int ch = 0; ch < NCH; ++ch) {
        size_t o = base + ((size_t)(b * NCH + ch) << 14) + cs;
        float Pv = chPH[o], Hv = chH[o];
        chPH[o] = h;
        h = fmaf(Pv, h, Hv);
    }
}

__global__ __launch_bounds__(256)
void scan_p3(const short* __restrict__ xzb,
             short* __restrict__ xcb,           // xc in, ybar out (in place)
             const float* __restrict__ BCb,
             const float* __restrict__ A_log0, const float* __restrict__ A_log1,
             const float* __restrict__ Dp0, const float* __restrict__ Dp1,
             const float* __restrict__ hst)
{
    __shared__ float Bs[CHUNK][16];
    __shared__ float Cs[CHUNK][16];
    const int tid = threadIdx.x;
    const int blk = blockIdx.x;
    const int dir = blk >> 8;
    const int rr  = blk & 255;
    const int cb = rr & 3;
    const int ch = (rr >> 2) & (NCH - 1);
    const int b  = rr >> 7;
    const int c  = cb * 256 + tid;
    const int rev = dir;

    const int u0 = rev ? (SEQ - 1 - ch * CHUNK) : (ch * CHUNK);
    const int st = rev ? -1 : 1;
    const float* A_log = dir ? A_log1 : A_log0;
    const float* Dp    = dir ? Dp1 : Dp0;
    const float* bcD = BCb + (size_t)dir * BC_STR;

    for (int r = tid; r < CHUNK * 16; r += 256) {
        int i = r >> 4, s = r & 15;
        int row = b * SEQ + u0 + st * i;
        Bs[i][s] = bcD[(size_t)row * 32 + s];
        Cs[i][s] = bcD[(size_t)row * 32 + 16 + s];
    }

    float Acs[16];
#pragma unroll
    for (int s = 0; s < 16; ++s)
        Acs[s] = -__expf(A_log[c * 16 + s]) * 1.44269504f;

    const float Dc = Dp[c];

    float h[16];
    size_t o = (size_t)dir * CH_STR + ((size_t)(b * NCH + ch) * 1024 + c) * 16;
#pragma unroll
    for (int q = 0; q < 4; ++q) {
        float4 hv = *(const float4*)&hst[o + q * 4];
        h[q*4] = hv.x; h[q*4+1] = hv.y; h[q*4+2] = hv.z; h[q*4+3] = hv.w;
    }

    __syncthreads();

    const short* dtp = xzb + (size_t)(b * SEQ + u0) * 4096 + dir * 2048 + c;
    const short* zp  = xzb + (size_t)(b * SEQ + u0) * 4096 + dir * 2048 + 1024 + c;
    short*       xcp = xcb + (size_t)dir * XCB_STR + (size_t)(b * SEQ + u0) * D_INNER + c;
    const ptrdiff_t dstep = (ptrdiff_t)st * 4096;
    const ptrdiff_t xstep = (ptrdiff_t)st * D_INNER;

    float dt_r[PG], xc_r[PG], z_r[PG];
#pragma unroll
    for (int j = 0; j < PG; ++j) {
        dt_r[j] = bf2f(dtp[dstep * j]);
        xc_r[j] = bf2f(xcp[xstep * j]);
        z_r[j]  = bf2f(zp[dstep * j]);
    }

#pragma unroll 1
    for (int g = 0; g < NPG; ++g) {
        const int gg = (g + 1 < NPG) ? (g + 1) : g;
        float dt_n[PG], xc_n[PG], z_n[PG];
#pragma unroll
        for (int j = 0; j < PG; ++j) {
            int i = gg * PG + j;
            dt_n[j] = bf2f(dtp[dstep * i]);
            xc_n[j] = bf2f(xcp[xstep * i]);
            z_n[j]  = bf2f(zp[dstep * i]);
        }
#pragma unroll
        for (int j = 0; j < PG; ++j) {
            int i = g * PG + j;
            float dtv = dt_r[j];
            float xcv = xc_r[j];
            float e = dtv * xcv;
            float y = 0.f;
#pragma unroll
            for (int s = 0; s < 16; ++s) {
                float da = __builtin_amdgcn_exp2f(dtv * Acs[s]);
                h[s] = fmaf(da, h[s], e * Bs[i][s]);
                y = fmaf(h[s], Cs[i][s], y);
            }
            y = fmaf(Dc, xcv, y);
            float zv = z_r[j];
            float sig = 1.f / (1.f + __expf(-zv));
            xcp[xstep * i] = f2bf(y * zv * sig);   // ybar in place
        }
#pragma unroll
        for (int j = 0; j < PG; ++j) {
            dt_r[j] = dt_n[j]; xc_r[j] = xc_n[j]; z_r[j] = z_n[j];
        }
    }
}

extern "C" void kernel_launch(void* const* d_in, const int* in_sizes, int n_in,
                              void* d_out, int out_size, void* d_ws, size_t ws_size,
                              hipStream_t stream)
{
    const float* x = (const float*)d_in[0];
    float* out = (float*)d_out;
    float* ws  = (float*)d_ws;

    // workspace: 20,840,448 floats = 83.36 MB (< proven 92.27 MB)
    short* xzb  = (short*)ws;                    // [4096][4096] bf16  (8,388,608 fl)
    float* BCb  = ws + 8388608;                  // [2][4096][32] f32  (262,144 fl)
    float* chP  = ws + 8650752;                  // [2][CH_STR]        (2,097,152 fl)
    float* chH  = ws + 10747904;                 // [2][CH_STR]        (2,097,152 fl)
    short* Wcb  = (short*)(ws + 12845056);       // [2][1152][1024]    (1,179,648 fl)
    short* xbf  = (short*)(ws + 14024704);       // [4096][512] bf16   (1,048,576 fl)
    short* W1b  = (short*)(ws + 15073280);       // [4096][512] bf16   (1,048,576 fl)
    short* Wcat = (short*)(ws + 16121856);       // [512][2048] bf16   (524,288 fl)
    short* xcb  = (short*)(ws + 16646144);       // [2][4096][1024]    (4,194,304 fl)

    const int gElem = (NTOK * D_INNER + 255) / 256;

    // ---- shared prep ----
    cvt_bf16<<<(NTOK * DIM / 8 + 255) / 256, 256, 0, stream>>>(x, xbf, NTOK * DIM);
    cvt_bf16<<<(2 * D_INNER * DIM / 8 + 255) / 256, 256, 0, stream>>>(
        (const float*)d_in[1 + 0 * 9 + 0], W1b, 2 * D_INNER * DIM);
    cvt_bf16<<<(2 * D_INNER * DIM / 8 + 255) / 256, 256, 0, stream>>>(
        (const float*)d_in[1 + 1 * 9 + 0], W1b + 2 * D_INNER * DIM, 2 * D_INNER * DIM);
    cvt_wcat<<<(512 * 2048 + 255) / 256, 256, 0, stream>>>(
        (const float*)d_in[1 + 0 * 9 + 8], (const float*)d_in[1 + 1 * 9 + 8], Wcat);
    {
        dim3 g((NC_PAD * D_INNER + 255) / 256, 2);
        build_wc<<<g, 256, 0, stream>>>(
            (const float*)d_in[1 + 0 * 9 + 3], (const float*)d_in[1 + 1 * 9 + 3],
            (const float*)d_in[1 + 0 * 9 + 4], (const float*)d_in[1 + 1 * 9 + 4],
            Wcb);
    }

    // GEMM1: xzb = x @ [in_w_f; in_w_r]^T  [4096,4096] bf16, grid 32x32
    {
        dim3 g(4096 / 128, NTOK / 128, 1);
        gemm_bf16<0><<<g, 256, 0, stream>>>(xbf, xbf, DIM, DIM, W1b, DIM,
                                            xzb, 4096, DIM, 1.f, 2,
                                            nullptr, nullptr, nullptr, 0, 0);
    }
    // conv+SiLU both dirs -> xcb
    {
        dim3 g(gElem, 2);
        conv_silu_kernel<<<g, 256, 0, stream>>>(
            xzb,
            (const float*)d_in[1 + 0 * 9 + 1], (const float*)d_in[1 + 1 * 9 + 1],
            (const float*)d_in[1 + 0 * 9 + 2], (const float*)d_in[1 + 1 * 9 + 2],
            xcb);
    }
    // GEMM2 both dirs (fused fast softplus; dt->xzb xi-cols bf16, BC->BCb)
    {
        dim3 g(NC_PAD / 128, NTOK / 128, 2);   // 9 x 32 x 2 = 576 blocks
        gemm_bf16<0><<<g, 256, 0, stream>>>(xcb, xcb, D_INNER, D_INNER,
                                            Wcb, D_INNER,
                                            xzb, 0, D_INNER, 1.f, 3,
                                            (const float*)d_in[1 + 0 * 9 + 5],
                                            (const float*)d_in[1 + 1 * 9 + 5],
                                            BCb, XCB_STR, WCB_STR);
    }
    // scans, both dirs — CHUNK=64, 512 blocks
    scan_p1<<<512, 256, 0, stream>>>(xzb, xcb, BCb,
                                     (const float*)d_in[1 + 0 * 9 + 6],
                                     (const float*)d_in[1 + 1 * 9 + 6],
                                     chP, chH);
    scan_p2<<<(2 * B_SZ * 16384) / 256, 256, 0, stream>>>(chP, chH);
    scan_p3<<<512, 256, 0, stream>>>(xzb, xcb, BCb,
                                     (const float*)d_in[1 + 0 * 9 + 6],
                                     (const float*)d_in[1 + 1 * 9 + 6],
                                     (const float*)d_in[1 + 0 * 9 + 7],
                                     (const float*)d_in[1 + 1 * 9 + 7],
                                     chP);
    // GEMM3: out = 0.5 * [ybar_f | ybar_r] @ Wcat^T, K=2048 — 64^2 tile
    {
        dim3 g(DIM / 64, NTOK / 64, 1);
        gemm_bf16<1><<<g, 256, 0, stream>>>(xcb, xcb + XCB_STR, D_INNER, D_INNER,
                                            Wcat, 2 * D_INNER,
                                            out, DIM, 2 * D_INNER, 0.5f, 0,
                                            nullptr, nullptr, nullptr, 0, 0);
    }
}

// Round 32
// 249.758 us; speedup vs baseline: 1.1661x; 1.0164x over previous
//
#include <hip/hip_runtime.h>
#include <hip/hip_bf16.h>
#include <math.h>

#define DIM      512
#define D_STATE  16
#define D_CONV   4
#define D_INNER  1024
#define DT_RANK  32
#define B_SZ     2
#define SEQ      2048
#define NTOK     (B_SZ * SEQ)   // 4096
#define CHUNK    64
#define NCH      (SEQ / CHUNK)  // 32
#define NC_PAD   1152
#define PG       8
#define NPG      (CHUNK / PG)   // 8

// strides (elements)
#define XCB_STR   4194304   // [4096][1024] bf16 per dir (shorts)
#define WCB_STR   1179648   // [1152][1024] bf16 per dir (shorts)
#define BC_STR    131072    // [4096][32] fp32 per dir (floats)
#define CH_STR    1048576   // B_SZ*NCH*1024*16 fp32 per dir (floats)

typedef __attribute__((ext_vector_type(8))) short bf16x8;
typedef __attribute__((ext_vector_type(4))) float f32x4;

__device__ __forceinline__ short f2bf(float f) {
    unsigned u = __float_as_uint(f);
    u += 0x7fffu + ((u >> 16) & 1u);
    return (short)(u >> 16);
}
__device__ __forceinline__ float bf2f(short v) {
    return __uint_as_float(((unsigned)(unsigned short)v) << 16);
}
__device__ __forceinline__ float softplus_fast(float v) {
    return (v > 20.f) ? v : __logf(1.f + __expf(v));
}

// ---------------- fp32 -> bf16 bulk convert (n % 8 == 0) ------------------
__global__ __launch_bounds__(256)
void cvt_bf16(const float* __restrict__ src, short* __restrict__ dst, int n)
{
    int i = (blockIdx.x * 256 + threadIdx.x) * 8;
    if (i >= n) return;
    float4 a = *(const float4*)(src + i);
    float4 b = *(const float4*)(src + i + 4);
    bf16x8 v;
    v[0] = f2bf(a.x); v[1] = f2bf(a.y); v[2] = f2bf(a.z); v[3] = f2bf(a.w);
    v[4] = f2bf(b.x); v[5] = f2bf(b.y); v[6] = f2bf(b.z); v[7] = f2bf(b.w);
    *(bf16x8*)(dst + i) = v;
}

// Wcat[512][2048] = [out_w_f | out_w_r] along K (bf16)
__global__ __launch_bounds__(256)
void cvt_wcat(const float* __restrict__ wf, const float* __restrict__ wr,
              short* __restrict__ Wcat)
{
    int idx = blockIdx.x * 256 + threadIdx.x;
    if (idx >= 512 * 2048) return;
    int n = idx >> 11, col = idx & 2047;
    const float* src = (col < 1024) ? wf : wr;
    Wcat[idx] = f2bf(src[n * 1024 + (col & 1023)]);
}

// ---------------- combined projection weight, both dirs ------------------
__global__ __launch_bounds__(256)
void build_wc(const float* __restrict__ xp0, const float* __restrict__ xp1,
              const float* __restrict__ dw0, const float* __restrict__ dw1,
              short* __restrict__ Wcb)
{
    const int dir = blockIdx.y;
    int idx = blockIdx.x * 256 + threadIdx.x;
    if (idx >= NC_PAD * D_INNER) return;
    const float* xproj_w = dir ? xp1 : xp0;
    const float* dt_w    = dir ? dw1 : dw0;
    int i = idx >> 10, k = idx & 1023;
    float v;
    if (i < 1024) {
        v = 0.f;
#pragma unroll
        for (int r = 0; r < 32; ++r)
            v = fmaf(dt_w[i * 32 + r], xproj_w[r * 1024 + k], v);
    } else if (i < 1056) {
        v = xproj_w[(i - 1024 + 32) * 1024 + k];
    } else {
        v = 0.f;
    }
    Wcb[(size_t)dir * WCB_STR + idx] = f2bf(v);
}

// ---------------- MFMA GEMM (bf16): C (+)= alpha * [A|A2] @ W^T -------------
// CFG=0: 128x128/BK32 with 512 THREADS = 8 WAVES (2x4 wave grid, wave tile
//   64x32, 4x2 frags). Doubles waves/CU at fixed grid — the only untried
//   lever against the barrier-chain stall (grid is shape-capped). One chunk
//   per thread per matrix staging (ci = tid); same LDS layout as before.
// CFG=1: 64x64/BK64, 256 threads, unchanged (GEMM3, supports [A|A2] K-split).
// Both: reg-staged (1-deep) + LDS double buffer, ONE barrier per K-step.
// Fast hw transcendentals in cmode-3 epilogue. XCD swizzle.
// cmode: 0 = fp32 store, 2 = bf16 store, 3 = GEMM2 epilogue.
template<int CFG>
__global__ __launch_bounds__(CFG ? 256 : 512)
void gemm_bf16(const short* __restrict__ A, const short* __restrict__ A2,
               int lda, int K1,
               const short* __restrict__ W, int ldw,
               void* __restrict__ Cv, int ldc,
               int K, float alpha, int cmode,
               const float* __restrict__ dtb0, const float* __restrict__ dtb1,
               float* __restrict__ BCb, int aStr, int wStr)
{
    constexpr int TMc  = CFG ? 64 : 128;
    constexpr int TKc  = CFG ? 64 : 32;
    constexpr int FCM  = CFG ? 2 : 4;    // frags in m per wave
    constexpr int FCN  = 2;              // frags in n per wave
    constexpr int WTSM = CFG ? 32 : 64;  // wave tile m stride
    constexpr int WTSN = 32;             // wave tile n stride
    __shared__ __align__(16) short As[2][TMc * TKc];   // 2 x 8 KB
    __shared__ __align__(16) short Ws[2][TMc * TKc];

    // XCD swizzle (all grids have nwg % 8 == 0)
    const int nx = gridDim.x, ny = gridDim.y;
    const int nwg = nx * ny * gridDim.z;
    int lin = blockIdx.x + nx * (blockIdx.y + ny * blockIdx.z);
    int swz = (lin & 7) * (nwg >> 3) + (lin >> 3);
    const int bx = swz % nx;
    int tmp = swz / nx;
    const int by = tmp % ny;
    const int dir = tmp / ny;

    A  += (size_t)dir * aStr;
    A2 += (size_t)dir * aStr;
    W  += (size_t)dir * wStr;

    const int tid  = threadIdx.x;
    const int lane = tid & 63;
    const int wid  = tid >> 6;
    const int wr   = CFG ? (wid >> 1) : (wid >> 2);
    const int wc   = CFG ? (wid & 1)  : (wid & 3);
    const int m0 = by * TMc;
    const int n0 = bx * TMc;

    f32x4 acc[FCM][FCN] = {};
    const int nt = K / TKc;

    if constexpr (CFG == 0) {
        // staging: 512 chunks per matrix, thread tid stages chunk tid.
        // chunk ci -> row mblk*16+ml (mblk=ci>>6, ml=ci&15), k=kc*8 (kc=(ci>>4)&3)
        const int am0 = ((tid >> 6) << 4) | (tid & 15);
        const int kc0 = (tid >> 4) & 3;
        const size_t arow0 = (size_t)(m0 + am0) * lda + kc0 * 8;
        const short* pw0 = W + (size_t)(n0 + am0) * ldw + kc0 * 8;

        bf16x8 ra0, rw0;

#define LOADR(tt) do { const int off_ = (tt) * TKc;             \
        ra0 = *(const bf16x8*)(A + arow0 + off_);               \
        rw0 = *(const bf16x8*)(pw0 + off_); } while (0)
#define DSWRITE(buf) do {                                       \
        *(bf16x8*)(As[buf] + tid * 8) = ra0;                    \
        *(bf16x8*)(Ws[buf] + tid * 8) = rw0; } while (0)

        LOADR(0);
        DSWRITE(0);
        LOADR(1);
        __syncthreads();

        for (int t = 0; t < nt; ++t) {
            const int cur = t & 1;
            if (t + 1 < nt) DSWRITE(cur ^ 1);
            if (t + 2 < nt) LOADR(t + 2);

            bf16x8 af[4], bff[2];
#pragma unroll
            for (int f = 0; f < 4; ++f) {
                int ai = (wr * 4 + f) * 64 + (lane >> 4) * 16 + (lane & 15);
                af[f] = *(const bf16x8*)(&As[cur][ai * 8]);
            }
#pragma unroll
            for (int f = 0; f < 2; ++f) {
                int bi = (wc * 2 + f) * 64 + (lane >> 4) * 16 + (lane & 15);
                bff[f] = *(const bf16x8*)(&Ws[cur][bi * 8]);
            }
#pragma unroll
            for (int i = 0; i < 4; ++i)
#pragma unroll
                for (int j = 0; j < 2; ++j)
                    acc[i][j] = __builtin_amdgcn_mfma_f32_16x16x32_bf16(
                        af[i], bff[j], acc[i][j], 0, 0, 0);
            __syncthreads();
        }
#undef LOADR
#undef DSWRITE
    } else {
        const int am0 = ((tid >> 7) << 4) | (tid & 15);
        const int kc0 = (tid >> 4) & 7;
        const int rstep = 32;
        const size_t arow0 = (size_t)(m0 + am0) * lda + kc0 * 8;
        const size_t arow1 = arow0 + (size_t)rstep * lda;
        const short* pw0 = W + (size_t)(n0 + am0) * ldw + kc0 * 8;
        const short* pw1 = pw0 + (size_t)rstep * ldw;
        const int ci0 = tid, ci1 = tid + 256;

        bf16x8 ra0, ra1, rw0, rw1;

#define LOADR(tt) do {                                          \
    const int off_ = (tt) * TKc;                                \
    const short* ab_ = (off_ < K1) ? A : A2;                    \
    const int ao_ = (off_ < K1) ? off_ : off_ - K1;             \
    ra0 = *(const bf16x8*)(ab_ + arow0 + ao_);                  \
    ra1 = *(const bf16x8*)(ab_ + arow1 + ao_);                  \
    rw0 = *(const bf16x8*)(pw0 + off_);                         \
    rw1 = *(const bf16x8*)(pw1 + off_); } while (0)

#define DSWRITE(buf) do {                                       \
    *(bf16x8*)(As[buf] + ci0 * 8) = ra0;                        \
    *(bf16x8*)(As[buf] + ci1 * 8) = ra1;                        \
    *(bf16x8*)(Ws[buf] + ci0 * 8) = rw0;                        \
    *(bf16x8*)(Ws[buf] + ci1 * 8) = rw1; } while (0)

        LOADR(0);
        DSWRITE(0);
        LOADR(1);
        __syncthreads();

        for (int t = 0; t < nt; ++t) {
            const int cur = t & 1;
            if (t + 1 < nt) DSWRITE(cur ^ 1);
            if (t + 2 < nt) LOADR(t + 2);

            bf16x8 af[2][2], bff[2][2];
#pragma unroll
            for (int f = 0; f < 2; ++f)
#pragma unroll
                for (int ks = 0; ks < 2; ++ks) {
                    int ai = (wr * 2 + f) * 128 + ks * 64 + (lane >> 4) * 16 + (lane & 15);
                    af[f][ks] = *(const bf16x8*)(&As[cur][ai * 8]);
                    int bi = (wc * 2 + f) * 128 + ks * 64 + (lane >> 4) * 16 + (lane & 15);
                    bff[f][ks] = *(const bf16x8*)(&Ws[cur][bi * 8]);
                }
#pragma unroll
            for (int i = 0; i < 2; ++i)
#pragma unroll
                for (int j = 0; j < 2; ++j) {
                    acc[i][j] = __builtin_amdgcn_mfma_f32_16x16x32_bf16(
                        af[i][0], bff[j][0], acc[i][j], 0, 0, 0);
                    acc[i][j] = __builtin_amdgcn_mfma_f32_16x16x32_bf16(
                        af[i][1], bff[j][1], acc[i][j], 0, 0, 0);
                }
            __syncthreads();
        }
#undef LOADR
#undef DSWRITE
    }

    if (cmode == 2) {
        short* C = (short*)Cv;
#pragma unroll
        for (int i = 0; i < FCM; ++i) {
            int row = m0 + wr * WTSM + i * 16 + ((lane >> 4) << 2);
#pragma unroll
            for (int j = 0; j < FCN; ++j) {
                int col = n0 + wc * WTSN + j * 16 + (lane & 15);
#pragma unroll
                for (int r = 0; r < 4; ++r)
                    C[(size_t)(row + r) * ldc + col] = f2bf(alpha * acc[i][j][r]);
            }
        }
    } else if (cmode == 3) {
        if (n0 < 1024) {
            short* dtO = (short*)Cv;   // xzb base
            const float* dtb = dir ? dtb1 : dtb0;
#pragma unroll
            for (int i = 0; i < FCM; ++i) {
                int row = m0 + wr * WTSM + i * 16 + ((lane >> 4) << 2);
#pragma unroll
                for (int j = 0; j < FCN; ++j) {
                    int col = n0 + wc * WTSN + j * 16 + (lane & 15);
                    float bias = dtb[col];
#pragma unroll
                    for (int r = 0; r < 4; ++r) {
                        float v = softplus_fast(acc[i][j][r] + bias);
                        dtO[(size_t)(row + r) * 4096 + dir * 2048 + col] = f2bf(v);
                    }
                }
            }
        } else {
            float* bc = BCb + (size_t)dir * BC_STR;
#pragma unroll
            for (int i = 0; i < FCM; ++i) {
                int row = m0 + wr * WTSM + i * 16 + ((lane >> 4) << 2);
#pragma unroll
                for (int j = 0; j < FCN; ++j) {
                    int col = n0 + wc * WTSN + j * 16 + (lane & 15);
                    if (col < 1056) {
#pragma unroll
                        for (int r = 0; r < 4; ++r)
                            bc[(size_t)(row + r) * 32 + (col - 1024)] = acc[i][j][r];
                    }
                }
            }
        }
    } else {
        float* C = (float*)Cv;
#pragma unroll
        for (int i = 0; i < FCM; ++i) {
            int row = m0 + wr * WTSM + i * 16 + ((lane >> 4) << 2);
#pragma unroll
            for (int j = 0; j < FCN; ++j) {
                int col = n0 + wc * WTSN + j * 16 + (lane & 15);
#pragma unroll
                for (int r = 0; r < 4; ++r)
                    C[(size_t)(row + r) * ldc + col] = alpha * acc[i][j][r];
            }
        }
    }
}

// ---------------- depthwise conv (k=4) + bias + SiLU, both dirs -----------
__global__ __launch_bounds__(256)
void conv_silu_kernel(const short* __restrict__ xzb,
                      const float* __restrict__ cw0, const float* __restrict__ cw1,
                      const float* __restrict__ cb0, const float* __restrict__ cb1,
                      short* __restrict__ xcb)
{
    const int rev = blockIdx.y;
    int idx = blockIdx.x * 256 + threadIdx.x;
    if (idx >= NTOK * D_INNER) return;
    int c   = idx & (D_INNER - 1);
    int row = idx >> 10;
    int b   = row / SEQ;
    int u   = row - b * SEQ;
    const int coff = rev * 2048 + c;
    const float* cw = rev ? cw1 : cw0;
    const float* cb = rev ? cb1 : cb0;

    float w0 = cw[c * 4 + 0], w1 = cw[c * 4 + 1];
    float w2 = cw[c * 4 + 2], w3 = cw[c * 4 + 3];
    float accv = cb[c];
    if (!rev) {
#pragma unroll
        for (int k = 0; k < 4; ++k) {
            int uu = u - 3 + k;
            float wv = (k == 0) ? w0 : (k == 1) ? w1 : (k == 2) ? w2 : w3;
            if (uu >= 0)
                accv = fmaf(wv, bf2f(xzb[(size_t)(b * SEQ + uu) * 4096 + coff]), accv);
        }
    } else {
#pragma unroll
        for (int k = 0; k < 4; ++k) {
            int uu = u + 3 - k;
            float wv = (k == 0) ? w0 : (k == 1) ? w1 : (k == 2) ? w2 : w3;
            if (uu < SEQ)
                accv = fmaf(wv, bf2f(xzb[(size_t)(b * SEQ + uu) * 4096 + coff]), accv);
        }
    }
    float r = accv / (1.f + __expf(-accv));
    xcb[(size_t)rev * XCB_STR + idx] = f2bf(r);
}

// ---------------- chunked SSM scan, both dirs, CHUNK=64 -------------------
__global__ __launch_bounds__(256)
void scan_p1(const short* __restrict__ xzb,
             const short* __restrict__ xcb,
             const float* __restrict__ BCb,
             const float* __restrict__ A_log0, const float* __restrict__ A_log1,
             float* __restrict__ chP, float* __restrict__ chH)
{
    __shared__ float Bs[CHUNK][16];
    const int tid = threadIdx.x;
    const int blk = blockIdx.x;
    const int dir = blk >> 8;
    const int rr  = blk & 255;
    const int cb = rr & 3;
    const int ch = (rr >> 2) & (NCH - 1);
    const int b  = rr >> 7;
    const int c  = cb * 256 + tid;
    const int rev = dir;

    const int u0 = rev ? (SEQ - 1 - ch * CHUNK) : (ch * CHUNK);
    const int st = rev ? -1 : 1;
    const float* A_log = dir ? A_log1 : A_log0;
    const float* bcD = BCb + (size_t)dir * BC_STR;

    for (int r = tid; r < CHUNK * 16; r += 256) {
        int i = r >> 4, s = r & 15;
        int row = b * SEQ + u0 + st * i;
        Bs[i][s] = bcD[(size_t)row * 32 + s];
    }

    float Acs[16];
#pragma unroll
    for (int s = 0; s < 16; ++s)
        Acs[s] = -__expf(A_log[c * 16 + s]) * 1.44269504f;

    float h[16];
    float dts = 0.f;   // P[s] = exp2(Acs[s] * sum(dt))
#pragma unroll
    for (int s = 0; s < 16; ++s) h[s] = 0.f;

    __syncthreads();

    const short* dtp = xzb + (size_t)(b * SEQ + u0) * 4096 + dir * 2048 + c;
    const short* xcp = xcb + (size_t)dir * XCB_STR + (size_t)(b * SEQ + u0) * D_INNER + c;
    const ptrdiff_t dstep = (ptrdiff_t)st * 4096;
    const ptrdiff_t xstep = (ptrdiff_t)st * D_INNER;

    float dt_r[PG], xc_r[PG];
#pragma unroll
    for (int j = 0; j < PG; ++j) {
        dt_r[j] = bf2f(dtp[dstep * j]);
        xc_r[j] = bf2f(xcp[xstep * j]);
    }

#pragma unroll 1
    for (int g = 0; g < NPG; ++g) {
        const int gg = (g + 1 < NPG) ? (g + 1) : g;
        float dt_n[PG], xc_n[PG];
#pragma unroll
        for (int j = 0; j < PG; ++j) {
            int i = gg * PG + j;
            dt_n[j] = bf2f(dtp[dstep * i]);
            xc_n[j] = bf2f(xcp[xstep * i]);
        }
#pragma unroll
        for (int j = 0; j < PG; ++j) {
            int i = g * PG + j;
            float dtv = dt_r[j];
            float e = dtv * xc_r[j];
            dts += dtv;
#pragma unroll
            for (int s = 0; s < 16; ++s) {
                float da = __builtin_amdgcn_exp2f(dtv * Acs[s]);
                h[s] = fmaf(da, h[s], e * Bs[i][s]);
            }
        }
#pragma unroll
        for (int j = 0; j < PG; ++j) { dt_r[j] = dt_n[j]; xc_r[j] = xc_n[j]; }
    }

    size_t o = (size_t)dir * CH_STR + ((size_t)(b * NCH + ch) * 1024 + c) * 16;
#pragma unroll
    for (int q = 0; q < 4; ++q) {
        float4 pv;
        pv.x = __builtin_amdgcn_exp2f(Acs[q*4+0] * dts);
        pv.y = __builtin_amdgcn_exp2f(Acs[q*4+1] * dts);
        pv.z = __builtin_amdgcn_exp2f(Acs[q*4+2] * dts);
        pv.w = __builtin_amdgcn_exp2f(Acs[q*4+3] * dts);
        *(float4*)&chP[o + q * 4] = pv;
        *(float4*)&chH[o + q * 4] = make_float4(h[q*4], h[q*4+1], h[q*4+2], h[q*4+3]);
    }
}

__global__ __launch_bounds__(256)
void scan_p2(float* __restrict__ chPH, const float* __restrict__ chH)
{
    int idx = blockIdx.x * 256 + threadIdx.x;   // [0, 2*B_SZ*16384)
    int dir = idx >> 15;
    int rem = idx & 32767;
    int b  = rem >> 14;
    int cs = rem & 16383;
    size_t base = (size_t)dir * CH_STR;
    float h = 0.f;
#pragma unroll
    for (int ch = 0; ch < NCH; ++ch) {
        size_t o = base + ((size_t)(b * NCH + ch) << 14) + cs;
        float Pv = chPH[o], Hv = chH[o];
        chPH[o] = h;
        h = fmaf(Pv, h, Hv);
    }
}

__global__ __launch_bounds__(256)
void scan_p3(const short* __restrict__ xzb,
             short* __restrict__ xcb,           // xc in, ybar out (in place)
             const float* __restrict__ BCb,
             const float* __restrict__ A_log0, const float* __restrict__ A_log1,
             const float* __restrict__ Dp0, const float* __restrict__ Dp1,
             const float* __restrict__ hst)
{
    __shared__ float Bs[CHUNK][16];
    __shared__ float Cs[CHUNK][16];
    const int tid = threadIdx.x;
    const int blk = blockIdx.x;
    const int dir = blk >> 8;
    const int rr  = blk & 255;
    const int cb = rr & 3;
    const int ch = (rr >> 2) & (NCH - 1);
    const int b  = rr >> 7;
    const int c  = cb * 256 + tid;
    const int rev = dir;

    const int u0 = rev ? (SEQ - 1 - ch * CHUNK) : (ch * CHUNK);
    const int st = rev ? -1 : 1;
    const float* A_log = dir ? A_log1 : A_log0;
    const float* Dp    = dir ? Dp1 : Dp0;
    const float* bcD = BCb + (size_t)dir * BC_STR;

    for (int r = tid; r < CHUNK * 16; r += 256) {
        int i = r >> 4, s = r & 15;
        int row = b * SEQ + u0 + st * i;
        Bs[i][s] = bcD[(size_t)row * 32 + s];
        Cs[i][s] = bcD[(size_t)row * 32 + 16 + s];
    }

    float Acs[16];
#pragma unroll
    for (int s = 0; s < 16; ++s)
        Acs[s] = -__expf(A_log[c * 16 + s]) * 1.44269504f;

    const float Dc = Dp[c];

    float h[16];
    size_t o = (size_t)dir * CH_STR + ((size_t)(b * NCH + ch) * 1024 + c) * 16;
#pragma unroll
    for (int q = 0; q < 4; ++q) {
        float4 hv = *(const float4*)&hst[o + q * 4];
        h[q*4] = hv.x; h[q*4+1] = hv.y; h[q*4+2] = hv.z; h[q*4+3] = hv.w;
    }

    __syncthreads();

    const short* dtp = xzb + (size_t)(b * SEQ + u0) * 4096 + dir * 2048 + c;
    const short* zp  = xzb + (size_t)(b * SEQ + u0) * 4096 + dir * 2048 + 1024 + c;
    short*       xcp = xcb + (size_t)dir * XCB_STR + (size_t)(b * SEQ + u0) * D_INNER + c;
    const ptrdiff_t dstep = (ptrdiff_t)st * 4096;
    const ptrdiff_t xstep = (ptrdiff_t)st * D_INNER;

    float dt_r[PG], xc_r[PG], z_r[PG];
#pragma unroll
    for (int j = 0; j < PG; ++j) {
        dt_r[j] = bf2f(dtp[dstep * j]);
        xc_r[j] = bf2f(xcp[xstep * j]);
        z_r[j]  = bf2f(zp[dstep * j]);
    }

#pragma unroll 1
    for (int g = 0; g < NPG; ++g) {
        const int gg = (g + 1 < NPG) ? (g + 1) : g;
        float dt_n[PG], xc_n[PG], z_n[PG];
#pragma unroll
        for (int j = 0; j < PG; ++j) {
            int i = gg * PG + j;
            dt_n[j] = bf2f(dtp[dstep * i]);
            xc_n[j] = bf2f(xcp[xstep * i]);
            z_n[j]  = bf2f(zp[dstep * i]);
        }
#pragma unroll
        for (int j = 0; j < PG; ++j) {
            int i = g * PG + j;
            float dtv = dt_r[j];
            float xcv = xc_r[j];
            float e = dtv * xcv;
            float y = 0.f;
#pragma unroll
            for (int s = 0; s < 16; ++s) {
                float da = __builtin_amdgcn_exp2f(dtv * Acs[s]);
                h[s] = fmaf(da, h[s], e * Bs[i][s]);
                y = fmaf(h[s], Cs[i][s], y);
            }
            y = fmaf(Dc, xcv, y);
            float zv = z_r[j];
            float sig = 1.f / (1.f + __expf(-zv));
            xcp[xstep * i] = f2bf(y * zv * sig);   // ybar in place
        }
#pragma unroll
        for (int j = 0; j < PG; ++j) {
            dt_r[j] = dt_n[j]; xc_r[j] = xc_n[j]; z_r[j] = z_n[j];
        }
    }
}

extern "C" void kernel_launch(void* const* d_in, const int* in_sizes, int n_in,
                              void* d_out, int out_size, void* d_ws, size_t ws_size,
                              hipStream_t stream)
{
    const float* x = (const float*)d_in[0];
    float* out = (float*)d_out;
    float* ws  = (float*)d_ws;

    // workspace: 20,840,448 floats = 83.36 MB (< proven 92.27 MB)
    short* xzb  = (short*)ws;                    // [4096][4096] bf16  (8,388,608 fl)
    float* BCb  = ws + 8388608;                  // [2][4096][32] f32  (262,144 fl)
    float* chP  = ws + 8650752;                  // [2][CH_STR]        (2,097,152 fl)
    float* chH  = ws + 10747904;                 // [2][CH_STR]        (2,097,152 fl)
    short* Wcb  = (short*)(ws + 12845056);       // [2][1152][1024]    (1,179,648 fl)
    short* xbf  = (short*)(ws + 14024704);       // [4096][512] bf16   (1,048,576 fl)
    short* W1b  = (short*)(ws + 15073280);       // [4096][512] bf16   (1,048,576 fl)
    short* Wcat = (short*)(ws + 16121856);       // [512][2048] bf16   (524,288 fl)
    short* xcb  = (short*)(ws + 16646144);       // [2][4096][1024]    (4,194,304 fl)

    const int gElem = (NTOK * D_INNER + 255) / 256;

    // ---- shared prep ----
    cvt_bf16<<<(NTOK * DIM / 8 + 255) / 256, 256, 0, stream>>>(x, xbf, NTOK * DIM);
    cvt_bf16<<<(2 * D_INNER * DIM / 8 + 255) / 256, 256, 0, stream>>>(
        (const float*)d_in[1 + 0 * 9 + 0], W1b, 2 * D_INNER * DIM);
    cvt_bf16<<<(2 * D_INNER * DIM / 8 + 255) / 256, 256, 0, stream>>>(
        (const float*)d_in[1 + 1 * 9 + 0], W1b + 2 * D_INNER * DIM, 2 * D_INNER * DIM);
    cvt_wcat<<<(512 * 2048 + 255) / 256, 256, 0, stream>>>(
        (const float*)d_in[1 + 0 * 9 + 8], (const float*)d_in[1 + 1 * 9 + 8], Wcat);
    {
        dim3 g((NC_PAD * D_INNER + 255) / 256, 2);
        build_wc<<<g, 256, 0, stream>>>(
            (const float*)d_in[1 + 0 * 9 + 3], (const float*)d_in[1 + 1 * 9 + 3],
            (const float*)d_in[1 + 0 * 9 + 4], (const float*)d_in[1 + 1 * 9 + 4],
            Wcb);
    }

    // GEMM1: xzb = x @ [in_w_f; in_w_r]^T  [4096,4096] bf16, grid 32x32, 512 thr
    {
        dim3 g(4096 / 128, NTOK / 128, 1);
        gemm_bf16<0><<<g, 512, 0, stream>>>(xbf, xbf, DIM, DIM, W1b, DIM,
                                            xzb, 4096, DIM, 1.f, 2,
                                            nullptr, nullptr, nullptr, 0, 0);
    }
    // conv+SiLU both dirs -> xcb
    {
        dim3 g(gElem, 2);
        conv_silu_kernel<<<g, 256, 0, stream>>>(
            xzb,
            (const float*)d_in[1 + 0 * 9 + 1], (const float*)d_in[1 + 1 * 9 + 1],
            (const float*)d_in[1 + 0 * 9 + 2], (const float*)d_in[1 + 1 * 9 + 2],
            xcb);
    }
    // GEMM2 both dirs (fused fast softplus; dt->xzb xi-cols bf16, BC->BCb), 512 thr
    {
        dim3 g(NC_PAD / 128, NTOK / 128, 2);   // 9 x 32 x 2 = 576 blocks
        gemm_bf16<0><<<g, 512, 0, stream>>>(xcb, xcb, D_INNER, D_INNER,
                                            Wcb, D_INNER,
                                            xzb, 0, D_INNER, 1.f, 3,
                                            (const float*)d_in[1 + 0 * 9 + 5],
                                            (const float*)d_in[1 + 1 * 9 + 5],
                                            BCb, XCB_STR, WCB_STR);
    }
    // scans, both dirs — CHUNK=64, 512 blocks
    scan_p1<<<512, 256, 0, stream>>>(xzb, xcb, BCb,
                                     (const float*)d_in[1 + 0 * 9 + 6],
                                     (const float*)d_in[1 + 1 * 9 + 6],
                                     chP, chH);
    scan_p2<<<(2 * B_SZ * 16384) / 256, 256, 0, stream>>>(chP, chH);
    scan_p3<<<512, 256, 0, stream>>>(xzb, xcb, BCb,
                                     (const float*)d_in[1 + 0 * 9 + 6],
                                     (const float*)d_in[1 + 1 * 9 + 6],
                                     (const float*)d_in[1 + 0 * 9 + 7],
                                     (const float*)d_in[1 + 1 * 9 + 7],
                                     chP);
    // GEMM3: out = 0.5 * [ybar_f | ybar_r] @ Wcat^T, K=2048 — 64^2 tile, 256 thr
    {
        dim3 g(DIM / 64, NTOK / 64, 1);
        gemm_bf16<1><<<g, 256, 0, stream>>>(xcb, xcb + XCB_STR, D_INNER, D_INNER,
                                            Wcat, 2 * D_INNER,
                                            out, DIM, 2 * D_INNER, 0.5f, 0,
                                            nullptr, nullptr, nullptr, 0, 0);
    }
}